// Round 6
// baseline (64676.068 us; speedup 1.0000x reference)
//
#include <hip/hip_runtime.h>

// NeuralCDEDecoder: B=512, T=257, IN=32, H=128, BN=256, OUT=64, K_SUB=4.
// R6: 8-way h-split. 256 blocks = 32 row-groups x 8 splits, 16 rows/block.
// Per-CU L2 stream/stage: W1 64K + W2 128K + W3/8 256K = 448KB (R5: 1.41MB;
// per-CU L2 port ~144GB/s is the bottleneck and scales with split factor).
// 7-partner z-exchange per stage: parity double-buffered slices + monotone
// flags (agent-scope atomics). Per-h arithmetic identical to R5 ->
// trajectory bit-identical (expected absmax exactly 0.7324219).
// Decoder partitioned across the 8 split-blocks (no duplicate writes).
// Weights packed in module __device__ globals (never d_ws: R1 corruption).

using short8   = __attribute__((ext_vector_type(8))) short;
using float4v  = __attribute__((ext_vector_type(4))) float;

__device__ unsigned short g_w1p[32768];
__device__ unsigned short g_w2p[65536];
__device__ unsigned short g_w3p[1048576];
__device__ unsigned short g_mwp[8192];
__device__ unsigned short g_swp[8192];

__device__ int   g_flag[256];                  // last stage posted per block
__device__ float g_zx[2 * 32 * 8 * 256];       // [parity][group][split][16rows*16dims]

__global__ void reset_flags(){
  if (threadIdx.x < 256) g_flag[threadIdx.x] = -1;
}

__device__ __forceinline__ unsigned short* pack_dst(int which){
  switch (which){
    case 0:  return g_w1p;
    case 1:  return g_w2p;
    case 2:  return g_w3p;
    case 3:  return g_mwp;
    default: return g_swp;
  }
}

__device__ __forceinline__ float bf2f(unsigned short h){
  union { unsigned int u; float f; } v; v.u = ((unsigned int)h) << 16; return v.f;
}
__device__ __forceinline__ unsigned short f2bf(float f){
  union { float f; unsigned int u; } v; v.f = f;
  unsigned int u = v.u;
  return (unsigned short)((u + 0x7FFFu + ((u >> 16) & 1u)) >> 16);  // RNE
}
template<bool BF16> __device__ __forceinline__ float loadf(const void* p, long i){
  if constexpr (BF16) return bf2f(((const unsigned short*)p)[i]);
  else                return ((const float*)p)[i];
}
// t[0]=0.0 always; bytes 2..3 are high half of f32 t[0] (=0) or bf16 t[1] (!=0).
__device__ __forceinline__ bool input_is_bf16(const void* t){
  return ((const unsigned short*)t)[1] != 0;
}
__device__ __forceinline__ float tanh_f(float x){
  float e = __builtin_amdgcn_exp2f(x * 2.88539008177793f);          // e^{2x}
  return 1.f - 2.f * __builtin_amdgcn_rcpf(e + 1.f);
}
__device__ __forceinline__ float softplus_f(float x){
  if (x > 20.f) return x;
  float e = __builtin_amdgcn_exp2f(x * 1.44269504088896f);
  return __builtin_amdgcn_logf(1.f + e) * 0.693147180559945f;       // log2->ln
}
// Sum across each 16-lane row; full sum lands in lane 15 of the row (VALU DPP).
__device__ __forceinline__ float row_sum16(float v){
  int x;
  x = __builtin_amdgcn_update_dpp(0, __float_as_int(v), 0x118, 0xF, 0xF, true); // row_shr:8
  v += __int_as_float(x);
  x = __builtin_amdgcn_update_dpp(0, __float_as_int(v), 0x114, 0xF, 0xF, true); // row_shr:4
  v += __int_as_float(x);
  x = __builtin_amdgcn_update_dpp(0, __float_as_int(v), 0x112, 0xF, 0xF, true); // row_shr:2
  v += __int_as_float(x);
  x = __builtin_amdgcn_update_dpp(0, __float_as_int(v), 0x111, 0xF, 0xF, true); // row_shr:1
  v += __int_as_float(x);
  return v;
}

// Pack row-major [K,N] weight into fragment order:
// tile (nt,kt) -> 512 bf16 at ((nt*KT+kt)<<9); elem (lane,j) = W[kt*32+(lane>>4)*8+j][nt*16+(lane&15)]
template<bool BF16>
__global__ __launch_bounds__(256)
void pack_weight(const void* __restrict__ src, int which,
                 int K, int N, const void* __restrict__ tchk){
  if (input_is_bf16(tchk) != BF16) return;
  unsigned short* dst = pack_dst(which);
  const int KT = K >> 5;
  const long total = (long)(N >> 4) * KT * 512;
  for (long e = (long)blockIdx.x * blockDim.x + threadIdx.x; e < total;
       e += (long)gridDim.x * blockDim.x){
    int  r    = (int)(e & 511);
    long tile = e >> 9;
    int  kt   = (int)(tile % KT);
    int  nt   = (int)(tile / KT);
    int  ln   = r >> 3, j = r & 7;
    int  k    = (kt << 5) + ((ln >> 4) << 3) + j;
    int  n    = (nt << 4) + (ln & 15);
    long si   = (long)k * N + n;
    dst[e] = BF16 ? ((const unsigned short*)src)[si] : f2bf(((const float*)src)[si]);
  }
}

#define STRZ 136   // z buffer row stride (bf16), 32 rows = hi/lo x 16 batch rows
#define STRH 264   // h buffer row stride (bf16), 32 rows = hi/lo x 16
#define STRV 132   // vf row stride (fp32), 16 rows, col = global h
#define STRD 33    // dxdt row stride (fp32), 16 rows

template<bool BF16>
__global__ __launch_bounds__(1024)
void cde_main(const void* __restrict__ tin,  const void* __restrict__ z0in,
              const void* __restrict__ Xin,
              const void* __restrict__ b1in, const void* __restrict__ b2in,
              const void* __restrict__ b3in, const void* __restrict__ mbin,
              const void* __restrict__ sbin,
              void* __restrict__ outv)
{
  if (input_is_bf16(tin) != BF16) return;

  const unsigned short* __restrict__ w1p = g_w1p;
  const unsigned short* __restrict__ w2p = g_w2p;
  const unsigned short* __restrict__ w3p = g_w3p;
  const unsigned short* __restrict__ mwp = g_mwp;
  const unsigned short* __restrict__ swp = g_swp;

  __shared__ __align__(16) unsigned short bufZ [32 * STRZ];
  __shared__ __align__(16) unsigned short bufH1[32 * STRH];
  __shared__ __align__(16) unsigned short bufH2[32 * STRH];
  __shared__ __align__(16) float          vfs  [16 * STRV];
  __shared__ __align__(16) float          dxs  [16 * STRD];
  __shared__ __align__(16) float          biasl[1152];  // b1|b2|b3-own|mb|sb

  const int tid  = threadIdx.x;
  const int lane = tid & 63;
  const int wv   = tid >> 6;          // wave 0..15
  const int c16  = lane & 15;         // MFMA A-row / B,D-col
  const int quad = lane >> 4;         // 0..3
  const int hb   = blockIdx.x & 7;    // split: owns h in [hb*16, hb*16+16)
  const int grp  = blockIdx.x >> 3;   // row group 0..31
  const int m0   = grp * 16;          // batch-row base (16 rows per group)
  const int Mt   = wv & 1;            // M-tile (8 batch rows each)
  const int ns   = wv >> 1;           // n-slot 0..7

  // biases -> LDS (fp32): b1[256] | b2[256] | b3-own[512] | mb[64] | sb[64]
  for (int i = tid; i < 1152; i += 1024){
    float v;
    if      (i < 256)  v = loadf<BF16>(b1in, i);
    else if (i < 512)  v = loadf<BF16>(b2in, i - 256);
    else if (i < 1024) v = loadf<BF16>(b3in, hb * 512 + (i - 512));
    else if (i < 1088) v = loadf<BF16>(mbin, i - 1024);
    else               v = loadf<BF16>(sbin, i - 1088);
    biasl[i] = v;
  }

  // per-thread z-state: thread owns 2 dims (zd0, zd0+1) of batch sub-row zm
  const int  zm   = tid >> 6;         // 0..15
  const int  zd0  = (tid & 63) << 1;  // 0,2,..,126
  const bool own  = (zd0 >> 4) == hb; // dims within this block's h-slice
  float z[2], zacc[2];
  #pragma unroll
  for (int r = 0; r < 2; ++r){
    z[r] = loadf<BF16>(z0in, (long)(m0 + zm) * 128 + zd0 + r);
    unsigned short h = f2bf(z[r]);
    bufZ[(2 * zm    ) * STRZ + zd0 + r] = h;
    bufZ[(2 * zm + 1) * STRZ + zd0 + r] = f2bf(z[r] - bf2f(h));
  }

  for (int ti = 0; ti < 256; ++ti){
    const float dt = loadf<BF16>(tin, ti + 1) - loadf<BF16>(tin, ti);
    const float hs = dt * 0.25f;                       // RK4 substep h
    if (tid < 512){
      const int m = tid >> 5, i = tid & 31;
      float xc = loadf<BF16>(Xin, ((long)(m0 + m) * 257 + ti    ) * 32 + i);
      float xn = loadf<BF16>(Xin, ((long)(m0 + m) * 257 + ti + 1) * 32 + i);
      dxs[m * STRD + i] = (xn - xc) / dt;
    }
    __syncthreads();                                   // dxs (and bufZ/bias) ready
    // dd[ih][s] = dxdt[row = Mt*8 + quad*2 + s][i = ih*16 + c16]
    float dd[2][2];
    #pragma unroll
    for (int ih = 0; ih < 2; ++ih)
      #pragma unroll
      for (int s = 0; s < 2; ++s)
        dd[ih][s] = dxs[(Mt * 8 + quad * 2 + s) * STRD + ih * 16 + c16];

    for (int sub = 0; sub < 4; ++sub){
      for (int st = 0; st < 4; ++st){
        const int stg = (ti << 4) + (sub << 2) + st;   // global stage 0..4095
        const int par = stg & 1;
        __syncthreads();                               // [A] stage input in bufZ

        // -------- layer 1: relu(z @ W1 + b1)  K=128 N=256 (2 ntiles/wave)
        {
          short8 a[4];
          #pragma unroll
          for (int kt = 0; kt < 4; ++kt)
            a[kt] = *(const short8*)&bufZ[(Mt * 16 + c16) * STRZ + kt * 32 + quad * 8];
          #pragma unroll
          for (int t2 = 0; t2 < 2; ++t2){
            const int nt = ns + t2 * 8;
            const unsigned short* wp = w1p + ((long)(nt * 4) << 9) + lane * 8;
            short8 b[4];
            #pragma unroll
            for (int kt = 0; kt < 4; ++kt) b[kt] = *(const short8*)(wp + (kt << 9));
            float4v acc = { 0.f, 0.f, 0.f, 0.f };
            #pragma unroll
            for (int kt = 0; kt < 4; ++kt)
              acc = __builtin_amdgcn_mfma_f32_16x16x32_bf16(a[kt], b[kt], acc, 0, 0, 0);
            const float bv = biasl[nt * 16 + c16];
            #pragma unroll
            for (int s = 0; s < 2; ++s){
              float v = acc[2 * s] + acc[2 * s + 1] + bv;
              v = v > 0.f ? v : 0.f;
              unsigned short h = f2bf(v);
              const int row = Mt * 16 + quad * 4 + 2 * s;
              bufH1[ row      * STRH + nt * 16 + c16] = h;
              bufH1[(row + 1) * STRH + nt * 16 + c16] = f2bf(v - bf2f(h));
            }
          }
        }
        __syncthreads();                               // [B]

        // -------- layer 2: relu(h1 @ W2 + b2)  K=256 N=256 (2 ntiles/wave)
        {
          short8 a[8];
          #pragma unroll
          for (int kt = 0; kt < 8; ++kt)
            a[kt] = *(const short8*)&bufH1[(Mt * 16 + c16) * STRH + kt * 32 + quad * 8];
          #pragma unroll
          for (int t2 = 0; t2 < 2; ++t2){
            const int nt = ns + t2 * 8;
            const unsigned short* wp = w2p + ((long)(nt * 8) << 9) + lane * 8;
            short8 b[8];
            #pragma unroll
            for (int kt = 0; kt < 8; ++kt) b[kt] = *(const short8*)(wp + (kt << 9));
            float4v acc = { 0.f, 0.f, 0.f, 0.f };
            #pragma unroll
            for (int kt = 0; kt < 8; ++kt)
              acc = __builtin_amdgcn_mfma_f32_16x16x32_bf16(a[kt], b[kt], acc, 0, 0, 0);
            const float bv = biasl[256 + nt * 16 + c16];
            #pragma unroll
            for (int s = 0; s < 2; ++s){
              float v = acc[2 * s] + acc[2 * s + 1] + bv;
              v = v > 0.f ? v : 0.f;
              unsigned short h = f2bf(v);
              const int row = Mt * 16 + quad * 4 + 2 * s;
              bufH2[ row      * STRH + nt * 16 + c16] = h;
              bufH2[(row + 1) * STRH + nt * 16 + c16] = f2bf(v - bf2f(h));
            }
          }
        }
        __syncthreads();                               // [C]

        // -------- layer 3 + contraction (own h-slice): 4 ntiles/wave
        // wave owns global ntiles hb*32 + ns*4 .. +3  -> h = hb*16 + ns*2 + {0,1}
        {
          short8 a[8];
          #pragma unroll
          for (int kt = 0; kt < 8; ++kt)
            a[kt] = *(const short8*)&bufH2[(Mt * 16 + c16) * STRH + kt * 32 + quad * 8];

          const int ntbase = hb * 32 + ns * 4;
          #pragma unroll 1
          for (int j = 0; j < 4; j += 2){
            float t0[2], t1[2];
            { // tile j: i in [0,16)
              const int nt = ntbase + j;
              const unsigned short* wp = w3p + ((long)(nt * 8) << 9) + lane * 8;
              short8 b[8];
              #pragma unroll
              for (int kt = 0; kt < 8; ++kt) b[kt] = *(const short8*)(wp + (kt << 9));
              float4v acc = { 0.f, 0.f, 0.f, 0.f };
              #pragma unroll
              for (int kt = 0; kt < 8; ++kt)
                acc = __builtin_amdgcn_mfma_f32_16x16x32_bf16(a[kt], b[kt], acc, 0, 0, 0);
              const float bv = biasl[512 + (nt - hb * 32) * 16 + c16];
              #pragma unroll
              for (int s = 0; s < 2; ++s)
                t0[s] = tanh_f(acc[2 * s] + acc[2 * s + 1] + bv) * dd[0][s];
            }
            { // tile j+1: i in [16,32) + reduce + vf write
              const int nt = ntbase + j + 1;
              const unsigned short* wp = w3p + ((long)(nt * 8) << 9) + lane * 8;
              short8 b[8];
              #pragma unroll
              for (int kt = 0; kt < 8; ++kt) b[kt] = *(const short8*)(wp + (kt << 9));
              float4v acc = { 0.f, 0.f, 0.f, 0.f };
              #pragma unroll
              for (int kt = 0; kt < 8; ++kt)
                acc = __builtin_amdgcn_mfma_f32_16x16x32_bf16(a[kt], b[kt], acc, 0, 0, 0);
              const float bv = biasl[512 + (nt - hb * 32) * 16 + c16];
              #pragma unroll
              for (int s = 0; s < 2; ++s)
                t1[s] = tanh_f(acc[2 * s] + acc[2 * s + 1] + bv) * dd[1][s];
              const int hg = (ntbase + j) >> 1;        // global h index
              #pragma unroll
              for (int s = 0; s < 2; ++s){
                float r = row_sum16(t0[s] + t1[s]);
                if (c16 == 15) vfs[(Mt * 8 + quad * 2 + s) * STRV + hg] = r;
              }
            }
          }
        }
        __syncthreads();                               // [D] own-slice vfs ready

        // -------- RK4 combine (own dims) + publish slice
        if (own){
          #pragma unroll
          for (int r = 0; r < 2; ++r){
            const float k = vfs[zm * STRV + zd0 + r];
            float nin;
            if (st == 0){
              zacc[r] = z[r] + (hs * (1.f / 6.f)) * k;
              nin     = z[r] + 0.5f * hs * k;
            } else if (st == 1){
              zacc[r] += (hs * (1.f / 3.f)) * k;
              nin      = z[r] + 0.5f * hs * k;
            } else if (st == 2){
              zacc[r] += (hs * (1.f / 3.f)) * k;
              nin      = z[r] + hs * k;
            } else {
              z[r] = zacc[r] + (hs * (1.f / 6.f)) * k;
              nin  = z[r];
            }
            __hip_atomic_store(
              (int*)&g_zx[(((par * 32 + grp) * 8 + hb) << 8) + zm * 16 + (zd0 & 15) + r],
              __float_as_int(nin), __ATOMIC_RELAXED, __HIP_MEMORY_SCOPE_AGENT);
            unsigned short h = f2bf(nin);
            bufZ[(2 * zm    ) * STRZ + zd0 + r] = h;
            bufZ[(2 * zm + 1) * STRZ + zd0 + r] = f2bf(nin - bf2f(h));
          }
        }
        __syncthreads();                               // [E] publish stores drained
        if (tid == 0)
          __hip_atomic_store(&g_flag[blockIdx.x], stg,
                             __ATOMIC_RELEASE, __HIP_MEMORY_SCOPE_AGENT);
        if (tid < 7){
          const int p = grp * 8 + ((hb + 1 + tid) & 7);
          while (__hip_atomic_load(&g_flag[p],
                                   __ATOMIC_ACQUIRE, __HIP_MEMORY_SCOPE_AGENT) < stg)
            __builtin_amdgcn_s_sleep(2);
        }
        __syncthreads();                               // [F] partner slices visible
        if (!own){
          const int sp = zd0 >> 4;                     // owning split of these dims
          #pragma unroll
          for (int r = 0; r < 2; ++r){
            int u = __hip_atomic_load(
              (const int*)&g_zx[(((par * 32 + grp) * 8 + sp) << 8) + zm * 16 + (zd0 & 15) + r],
              __ATOMIC_RELAXED, __HIP_MEMORY_SCOPE_AGENT);
            float v = __int_as_float(u);
            unsigned short h = f2bf(v);
            bufZ[(2 * zm    ) * STRZ + zd0 + r] = h;
            bufZ[(2 * zm + 1) * STRZ + zd0 + r] = f2bf(v - bf2f(h));
          }
        }
      } // st
    } // sub

    __syncthreads();                                   // bufZ holds z(t[ti+1])
    // -------- decoder, partitioned: 16 tasks over 8 split-blocks x 2 waves
    if (wv < 2){
      const int  task  = hb * 2 + wv;                  // 0..15
      const int  DMt   = task >> 3;
      const int  rr    = task & 7;
      const bool isStd = (rr >> 2) != 0;
      const int  nt    = rr & 3;
      short8 a[4];
      #pragma unroll
      for (int kt = 0; kt < 4; ++kt)
        a[kt] = *(const short8*)&bufZ[(DMt * 16 + c16) * STRZ + kt * 32 + quad * 8];
      const unsigned short* wp = (isStd ? swp : mwp) + ((long)(nt * 4) << 9) + lane * 8;
      short8 b[4];
      #pragma unroll
      for (int kt = 0; kt < 4; ++kt) b[kt] = *(const short8*)(wp + (kt << 9));
      float4v acc = { 0.f, 0.f, 0.f, 0.f };
      #pragma unroll
      for (int kt = 0; kt < 4; ++kt)
        acc = __builtin_amdgcn_mfma_f32_16x16x32_bf16(a[kt], b[kt], acc, 0, 0, 0);
      const float bv    = biasl[(isStd ? 1088 : 1024) + nt * 16 + c16];
      const long  obase = isStd ? 8388608L : 0L;       // B*(T-1)*OUT
      #pragma unroll
      for (int s = 0; s < 2; ++s){
        float v = acc[2 * s] + acc[2 * s + 1] + bv;
        if (isStd) v = softplus_f(v);
        long oi = obase + ((long)(m0 + DMt * 8 + quad * 2 + s) * 256 + ti) * 64 + nt * 16 + c16;
        if constexpr (BF16) ((unsigned short*)outv)[oi] = f2bf(v);
        else                ((float*)outv)[oi] = v;
      }
    }
  } // ti
}

extern "C" void kernel_launch(void* const* d_in, const int* in_sizes, int n_in,
                              void* d_out, int out_size, void* d_ws, size_t ws_size,
                              hipStream_t stream)
{
  const void* t  = d_in[0];
  const void* z0 = d_in[1];
  const void* X  = d_in[2];
  const void* W1 = d_in[3];
  const void* b1 = d_in[4];
  const void* W2 = d_in[5];
  const void* b2 = d_in[6];
  const void* W3 = d_in[7];
  const void* b3 = d_in[8];
  const void* mW = d_in[9];
  const void* mb = d_in[10];
  const void* sW = d_in[11];
  const void* sb = d_in[12];

  // Both dtype variants launched; each checks input dtype and the
  // non-matching one returns immediately (t[0]==0.0 discriminator).
  pack_weight<true ><<<256, 256, 0, stream>>>(W1, 0, 128,  256, t);
  pack_weight<true ><<<256, 256, 0, stream>>>(W2, 1, 256,  256, t);
  pack_weight<true ><<<512, 256, 0, stream>>>(W3, 2, 256, 4096, t);
  pack_weight<true ><<< 64, 256, 0, stream>>>(mW, 3, 128,   64, t);
  pack_weight<true ><<< 64, 256, 0, stream>>>(sW, 4, 128,   64, t);
  pack_weight<false><<<256, 256, 0, stream>>>(W1, 0, 128,  256, t);
  pack_weight<false><<<256, 256, 0, stream>>>(W2, 1, 256,  256, t);
  pack_weight<false><<<512, 256, 0, stream>>>(W3, 2, 256, 4096, t);
  pack_weight<false><<< 64, 256, 0, stream>>>(mW, 3, 128,   64, t);
  pack_weight<false><<< 64, 256, 0, stream>>>(sW, 4, 128,   64, t);

  reset_flags<<<1, 256, 0, stream>>>();               // stream-ordered before main

  cde_main<true ><<<256, 1024, 0, stream>>>(t, z0, X, b1, b2, b3, mb, sb, d_out);
  cde_main<false><<<256, 1024, 0, stream>>>(t, z0, X, b1, b2, b3, mb, sb, d_out);
  (void)in_sizes; (void)n_in; (void)out_size; (void)d_ws; (void)ws_size;
}